// Round 4
// baseline (187.577 us; speedup 1.0000x reference)
//
#include <hip/hip_runtime.h>

typedef unsigned short u16;
typedef unsigned int   u32;
typedef __bf16 bf16x8 __attribute__((ext_vector_type(8)));
typedef float  f32x4  __attribute__((ext_vector_type(4)));
typedef float  f32x16 __attribute__((ext_vector_type(16)));

#define TSEQ 2048
#define NHEAD 16
#define HDIM 64
#define CDIM 1024
#define N3   3072
#define MROWS 4096

__device__ __forceinline__ u16 f2bf(float f) {
    union { float f; u32 u; } v; v.f = f;
    u32 r = v.u + 0x7FFFu + ((v.u >> 16) & 1u);
    return (u16)(r >> 16);
}

// pack two fp32 -> packed bf16, 1-2 VALU ops.
__device__ __forceinline__ u32 pkbf(float a, float b) {
#if __has_builtin(__builtin_amdgcn_cvt_pk_bf16_f32)
    typedef __bf16 bf16x2 __attribute__((ext_vector_type(2)));
    bf16x2 t = __builtin_amdgcn_cvt_pk_bf16_f32(a, b);
    union { bf16x2 v; u32 u; } c; c.v = t; return c.u;
#else
    union { float f; u32 u; } ua, ub; ua.f = a; ub.f = b;
    u32 sel = 0x07060302, d;
    asm("v_perm_b32 %0, %1, %2, %3" : "=v"(d) : "v"(ub.u), "v"(ua.u), "v"(sel));
    return d;
#endif
}

// async global->LDS, 16B per lane (m97; GEMM staging only)
__device__ __forceinline__ void gld16(const u16* g, u16* l) {
    __builtin_amdgcn_global_load_lds(
        (const __attribute__((address_space(1))) u32*)g,
        (__attribute__((address_space(3))) u32*)l, 16, 0, 0);
}

// ---------------- merged prep: x->bf16 pack  +  both weight transposes ----------------
__global__ __launch_bounds__(256) void prep_kernel(const float* __restrict__ x,
                                                   const float* __restrict__ wqkv,
                                                   const float* __restrict__ wproj,
                                                   u16* __restrict__ Xb,
                                                   u16* __restrict__ oqkv, u16* __restrict__ oproj) {
    __shared__ float tile[32][33];
    const int bx = blockIdx.x;
    const int tid = threadIdx.x;
    if (bx < 4096) {  // pack region
        int i = bx * 256 + tid;
        float4 v = reinterpret_cast<const float4*>(x)[i];
        ushort4 o;
        o.x = f2bf(v.x); o.y = f2bf(v.y); o.z = f2bf(v.z); o.w = f2bf(v.w);
        reinterpret_cast<ushort4*>(Xb)[i] = o;
        return;
    }
    int idx = bx - 4096;
    int bnx = idx & 127;
    int k0  = (idx >> 7) * 32;
    const float* in; u16* out; int N, n0;
    if (bnx < 96) { in = wqkv;  out = oqkv;  N = 3072; n0 = bnx * 32; }
    else          { in = wproj; out = oproj; N = 1024; n0 = (bnx - 96) * 32; }
    int tx = tid & 31, ty = tid >> 5;  // (32, 8)
#pragma unroll
    for (int i = 0; i < 4; i++)
        tile[ty + i * 8][tx] = in[(size_t)(k0 + ty + i * 8) * N + n0 + tx];
    __syncthreads();
#pragma unroll
    for (int i = 0; i < 4; i++)
        out[(size_t)(n0 + ty + i * 8) * 1024 + k0 + tx] = f2bf(tile[tx][ty + i * 8]);
}

// ---------------- QKV GEMM: frag-order epilogue via LDS bounce (verified rounds 7/8) ----------------
// Qf chunk ((bh*64+qt)*4+kc): [lane=l5*32+q31][j] = Q[qt*32+q31][kc*16+l5*8+j]*c2
// Kf tile (bh*32+kb), chunk kc*2+nt: [lane][j] = K[nt*32+l31][kc*16+l5*8+j]
// Vf tile (bh*32+kb), chunk c*2+dt:  [lane][j] = V[c*16+(j>>2)*8+l5*4+(j&3)][dt*32+l31]
__global__ __launch_bounds__(256) void gemm_qkv(const u16* __restrict__ A, const u16* __restrict__ Bt,
                                                const float* __restrict__ bias, u16* __restrict__ Qf,
                                                u16* __restrict__ Kf, u16* __restrict__ Vf) {
    __shared__ __align__(16) u16 Al[128 * 32];
    __shared__ __align__(16) u16 Bl[128 * 32];
    __shared__ __align__(16) u16 Im[16384];
    const int tid  = threadIdx.x;
    const int lane = tid & 63;
    const int wave = tid >> 6;
    const int wm = (wave >> 1) * 64;
    const int wn = (wave & 1) * 64;
    const int row0 = blockIdx.x * 128;
    const int col0 = blockIdx.y * 128;
    const int lr = lane & 15;
    const int lq = lane >> 4;
    const float c2 = 0.125f * 1.44269504088896f;

    f32x4 acc[4][4];
#pragma unroll
    for (int i = 0; i < 4; i++)
#pragma unroll
        for (int j = 0; j < 4; j++) acc[i][j] = f32x4{0.f, 0.f, 0.f, 0.f};

    const int sr = tid >> 2, sc_ = (tid & 3) * 8;

    for (int k0 = 0; k0 < CDIM; k0 += 32) {
#pragma unroll
        for (int s = 0; s < 2; s++) {
            int i = tid + s * 256;
            int r = sr + s * 64;
            gld16(&A[(size_t)(row0 + r) * CDIM + k0 + sc_], &Al[i * 8]);
            gld16(&Bt[(size_t)(col0 + r) * CDIM + k0 + sc_], &Bl[i * 8]);
        }
        __syncthreads();
        bf16x8 af[4], bfr[4];
#pragma unroll
        for (int t = 0; t < 4; t++) {
            af[t]  = *reinterpret_cast<const bf16x8*>(&Al[(wm + t * 16 + lr) * 32 + lq * 8]);
            bfr[t] = *reinterpret_cast<const bf16x8*>(&Bl[(wn + t * 16 + lr) * 32 + lq * 8]);
        }
#pragma unroll
        for (int mt = 0; mt < 4; mt++)
#pragma unroll
            for (int nt = 0; nt < 4; nt++)
                acc[mt][nt] = __builtin_amdgcn_mfma_f32_16x16x32_bf16(af[mt], bfr[nt], acc[mt][nt], 0, 0, 0);
        __syncthreads();
    }

    const int region = col0 >> 10;
    const int h_base = (col0 & 1023) >> 6;
#pragma unroll
    for (int mt = 0; mt < 4; mt++) {
#pragma unroll
        for (int nt = 0; nt < 4; nt++) {
            int n_local = wn + nt * 16 + lr;
            float bv = bias[col0 + n_local];
            int h_local = n_local >> 6;
            int d = n_local & 63;
#pragma unroll
            for (int r = 0; r < 4; r++) {
                int m_local = wm + mt * 16 + lq * 4 + r;
                float v = acc[mt][nt][r] + bv;
                if (region == 0) {
                    int qt_local = m_local >> 5, q31 = m_local & 31;
                    int kc = d >> 4, l5b = (d >> 3) & 1, j = d & 7;
                    int lc = (h_local * 4 + qt_local) * 4 + kc;
                    Im[lc * 512 + (l5b * 32 + q31) * 8 + j] = f2bf(v * c2);
                } else if (region == 1) {
                    int kb_local = m_local >> 6, tr = m_local & 63;
                    int kc = d >> 4, l5b = (d >> 3) & 1, j = d & 7;
                    int nt2 = tr >> 5, p31 = tr & 31;
                    int lc = (h_local * 2 + kb_local) * 8 + kc * 2 + nt2;
                    Im[lc * 512 + (l5b * 32 + p31) * 8 + j] = f2bf(v);
                } else {
                    int kb_local = m_local >> 6, tr = m_local & 63;
                    int cV = tr >> 4, dt2 = d >> 5, p31 = d & 31;
                    int l5b = (tr >> 2) & 1;
                    int j = ((tr >> 3) & 1) * 4 + (tr & 3);
                    int lc = (h_local * 2 + kb_local) * 8 + cV * 2 + dt2;
                    Im[lc * 512 + (l5b * 32 + p31) * 8 + j] = f2bf(v);
                }
            }
        }
    }
    __syncthreads();
    const int bq = row0 >> 11;
    const int qrow0 = row0 & 2047;
#pragma unroll
    for (int s = 0; s < 8; s++) {
        int slot = s * 256 + tid;
        int lc = slot >> 6, li = slot & 63;
        uint4 data = *reinterpret_cast<const uint4*>(&Im[slot * 8]);
        if (region == 0) {
            int h_local = lc >> 4, qt_local = (lc >> 2) & 3, kc = lc & 3;
            size_t off = ((size_t)((bq * 16 + h_base + h_local) * 64 + (qrow0 >> 5) + qt_local) * 4 + kc) * 512
                       + li * 8;
            *reinterpret_cast<uint4*>(Qf + off) = data;
        } else {
            int h_local = lc >> 4, kb_local = (lc >> 3) & 1, cit = lc & 7;
            size_t off = (size_t)((bq * 16 + h_base + h_local) * 32 + (qrow0 >> 6) + kb_local) * 4096
                       + cit * 512 + li * 8;
            *reinterpret_cast<uint4*>((region == 1 ? Kf : Vf) + off) = data;
        }
    }
}

// ---------------- proj GEMM: 64x128 tile, BK=64 (2x BK=32 sub-tiles), fp32 out ----------------
__global__ __launch_bounds__(256) void gemm_proj(const u16* __restrict__ A, const u16* __restrict__ Bt,
                                                 const float* __restrict__ bias, float* __restrict__ C) {
    __shared__ __align__(16) u16 Al[2 * 64 * 32];    // [kk][64][32]
    __shared__ __align__(16) u16 Bl[2 * 128 * 32];   // [kk][128][32]
    const int tid  = threadIdx.x;
    const int lane = tid & 63;
    const int wave = tid >> 6;
    const int wm = (wave >> 1) * 32;
    const int wn = (wave & 1) * 64;
    const int row0 = blockIdx.x * 64;
    const int col0 = blockIdx.y * 128;
    const int lr = lane & 15;
    const int lq = lane >> 4;

    f32x4 acc[2][4];
#pragma unroll
    for (int i = 0; i < 2; i++)
#pragma unroll
        for (int j = 0; j < 4; j++) acc[i][j] = f32x4{0.f, 0.f, 0.f, 0.f};

    for (int k0 = 0; k0 < CDIM; k0 += 64) {
#pragma unroll
        for (int s = 0; s < 2; s++) {
            int i = tid + s * 256;
            int kk = i >> 8, rr = (i >> 2) & 63, cc = i & 3;
            gld16(&A[(size_t)(row0 + rr) * CDIM + k0 + kk * 32 + cc * 8], &Al[i * 8]);
        }
#pragma unroll
        for (int s = 0; s < 4; s++) {
            int i = tid + s * 256;
            int kk = i >> 9, rr = (i >> 2) & 127, cc = i & 3;
            gld16(&Bt[(size_t)(col0 + rr) * CDIM + k0 + kk * 32 + cc * 8], &Bl[i * 8]);
        }
        __syncthreads();
#pragma unroll
        for (int kk = 0; kk < 2; kk++) {
            bf16x8 af[2], bfr[4];
#pragma unroll
            for (int t = 0; t < 2; t++)
                af[t] = *reinterpret_cast<const bf16x8*>(&Al[kk * 2048 + (wm + t * 16 + lr) * 32 + lq * 8]);
#pragma unroll
            for (int t = 0; t < 4; t++)
                bfr[t] = *reinterpret_cast<const bf16x8*>(&Bl[kk * 4096 + (wn + t * 16 + lr) * 32 + lq * 8]);
#pragma unroll
            for (int mt = 0; mt < 2; mt++)
#pragma unroll
                for (int nt = 0; nt < 4; nt++)
                    acc[mt][nt] = __builtin_amdgcn_mfma_f32_16x16x32_bf16(af[mt], bfr[nt], acc[mt][nt], 0, 0, 0);
        }
        __syncthreads();
    }
#pragma unroll
    for (int mt = 0; mt < 2; mt++) {
#pragma unroll
        for (int nt = 0; nt < 4; nt++) {
            int col = col0 + wn + nt * 16 + lr;
            float bv = bias[col];
#pragma unroll
            for (int r = 0; r < 4; r++) {
                int row = row0 + wm + mt * 16 + lq * 4 + r;
                C[(size_t)row * CDIM + col] = acc[mt][nt][r] + bv;
            }
        }
    }
}

// ---------------- flash attention: split-KV — full ILP body x 2 waves/SIMD ----------------
// Round-4: 256 blocks x 512 threads. Waves 0-3 = round-0's verified 2-q-tile body over
// kb 0..15; waves 4-7 = same q-tiles over kb 16..31 (SIMD pairs 0/4,1/5,... co-resident).
// Softmax is non-max-subtracted (P=exp2 of prescaled S), so partials combine EXACTLY:
// O = O_lo + O_hi, l = l_lo + l_hi. Upper waves dump O (16x ds_write_b128, conflict-free
// [grp][lane] layout) + l to LDS; one barrier; lower waves add and run the old epilogue.
__global__ __launch_bounds__(512, 2) void attn_kernel(const u16* __restrict__ Qf,
                                                      const u16* __restrict__ Kf,
                                                      const u16* __restrict__ Vf,
                                                      u16* __restrict__ AO) {
    __shared__ __align__(16) float Ol[4][16][64][4];  // 64 KB [pair][grp][lane][4]
    __shared__ float Ll[4][64][2];                    // 2 KB
    const int id = blockIdx.x;            // 256 blocks; blocks of one (b,h) share id%8 -> same XCD
    const int bh = id & 31;
    const int qc = id >> 5;               // [0,8)
    const int b = bh >> 4, h = bh & 15;
    const int tid = threadIdx.x, lane = tid & 63, wave = tid >> 6;  // wave in [0,8)
    const int wp   = wave & 3;            // q-tile pair id
    const int half = wave >> 2;           // kb half: 0 -> kb 0..15, 1 -> kb 16..31
    const int l31 = lane & 31, l5 = lane >> 5;
    const int qt0 = qc * 8 + wp * 2;      // this pair's two 32-q tiles

    // Q B-frags (c2-prescaled), frag-ordered, coalesced
    bf16x8 qa0[4], qa1[4];
    {
        const u16* qp = Qf + ((size_t)(bh * 64 + qt0) * 4) * 512 + lane * 8;
#pragma unroll
        for (int kc = 0; kc < 4; kc++) {
            qa0[kc] = *reinterpret_cast<const bf16x8*>(qp + kc * 512);
            qa1[kc] = *reinterpret_cast<const bf16x8*>(qp + 2048 + kc * 512);
        }
    }
    f32x16 o00, o01, o10, o11, zc;
#pragma unroll
    for (int i = 0; i < 16; i++) { o00[i] = 0.f; o01[i] = 0.f; o10[i] = 0.f; o11[i] = 0.f; zc[i] = 0.f; }
    float la0[4], la1[4];
#pragma unroll
    for (int i = 0; i < 4; i++) { la0[i] = 0.f; la1[i] = 0.f; }

    const u16* kcur = Kf + ((size_t)bh * 32 + half * 16) * 4096 + lane * 8;
    const u16* vcur = Vf + ((size_t)bh * 32 + half * 16) * 4096 + lane * 8;

    bf16x8 ka[8];
#pragma unroll
    for (int i = 0; i < 8; i++) ka[i] = *reinterpret_cast<const bf16x8*>(kcur + i * 512);

    for (int kb = 0; kb < 16; kb++) {
        // V-frags issued FIRST: load latency hides under the QK^T MFMA cluster
        bf16x8 vfr[8];
#pragma unroll
        for (int i = 0; i < 8; i++) vfr[i] = *reinterpret_cast<const bf16x8*>(vcur + i * 512);
        // S^T = K * Q^T, 4 independent chains
        f32x16 st00, st01, st10, st11;
        __builtin_amdgcn_s_setprio(1);
        st00 = __builtin_amdgcn_mfma_f32_32x32x16_bf16(ka[0], qa0[0], zc, 0, 0, 0);
        st01 = __builtin_amdgcn_mfma_f32_32x32x16_bf16(ka[1], qa0[0], zc, 0, 0, 0);
        st10 = __builtin_amdgcn_mfma_f32_32x32x16_bf16(ka[0], qa1[0], zc, 0, 0, 0);
        st11 = __builtin_amdgcn_mfma_f32_32x32x16_bf16(ka[1], qa1[0], zc, 0, 0, 0);
#pragma unroll
        for (int kc = 1; kc < 4; kc++) {
            st00 = __builtin_amdgcn_mfma_f32_32x32x16_bf16(ka[kc * 2],     qa0[kc], st00, 0, 0, 0);
            st01 = __builtin_amdgcn_mfma_f32_32x32x16_bf16(ka[kc * 2 + 1], qa0[kc], st01, 0, 0, 0);
            st10 = __builtin_amdgcn_mfma_f32_32x32x16_bf16(ka[kc * 2],     qa1[kc], st10, 0, 0, 0);
            st11 = __builtin_amdgcn_mfma_f32_32x32x16_bf16(ka[kc * 2 + 1], qa1[kc], st11, 0, 0, 0);
        }
        __builtin_amdgcn_s_setprio(0);
        // prefetch next tile's K in place; latency hides under softmax
        const u16* knext = kcur + (kb < 15 ? 4096 : 0);
#pragma unroll
        for (int i = 0; i < 8; i++) ka[i] = *reinterpret_cast<const bf16x8*>(knext + i * 512);
        kcur = knext;
        vcur += 4096;
        // softmax: P = exp2(st) (prescaled; |st| < ~9, in range)
        bf16x8 pa0[4], pa1[4];
        {
            float pe[16];
            union { bf16x8 v; u32 w[4]; } ua, ub;
#pragma unroll
            for (int r = 0; r < 16; r++) { pe[r] = __builtin_amdgcn_exp2f(st00[r]); la0[r & 3] += pe[r]; }
#pragma unroll
            for (int j = 0; j < 4; j++) { ua.w[j] = pkbf(pe[2 * j], pe[2 * j + 1]); ub.w[j] = pkbf(pe[8 + 2 * j], pe[8 + 2 * j + 1]); }
            pa0[0] = ua.v; pa0[1] = ub.v;
#pragma unroll
            for (int r = 0; r < 16; r++) { pe[r] = __builtin_amdgcn_exp2f(st01[r]); la0[r & 3] += pe[r]; }
#pragma unroll
            for (int j = 0; j < 4; j++) { ua.w[j] = pkbf(pe[2 * j], pe[2 * j + 1]); ub.w[j] = pkbf(pe[8 + 2 * j], pe[8 + 2 * j + 1]); }
            pa0[2] = ua.v; pa0[3] = ub.v;
#pragma unroll
            for (int r = 0; r < 16; r++) { pe[r] = __builtin_amdgcn_exp2f(st10[r]); la1[r & 3] += pe[r]; }
#pragma unroll
            for (int j = 0; j < 4; j++) { ua.w[j] = pkbf(pe[2 * j], pe[2 * j + 1]); ub.w[j] = pkbf(pe[8 + 2 * j], pe[8 + 2 * j + 1]); }
            pa1[0] = ua.v; pa1[1] = ub.v;
#pragma unroll
            for (int r = 0; r < 16; r++) { pe[r] = __builtin_amdgcn_exp2f(st11[r]); la1[r & 3] += pe[r]; }
#pragma unroll
            for (int j = 0; j < 4; j++) { ua.w[j] = pkbf(pe[2 * j], pe[2 * j + 1]); ub.w[j] = pkbf(pe[8 + 2 * j], pe[8 + 2 * j + 1]); }
            pa1[2] = ua.v; pa1[3] = ub.v;
        }
        // O += P V (V rows pre-permuted to match P's register key order)
        __builtin_amdgcn_s_setprio(1);
#pragma unroll
        for (int c = 0; c < 4; c++) {
            o00 = __builtin_amdgcn_mfma_f32_32x32x16_bf16(pa0[c], vfr[c * 2],     o00, 0, 0, 0);
            o01 = __builtin_amdgcn_mfma_f32_32x32x16_bf16(pa0[c], vfr[c * 2 + 1], o01, 0, 0, 0);
            o10 = __builtin_amdgcn_mfma_f32_32x32x16_bf16(pa1[c], vfr[c * 2],     o10, 0, 0, 0);
            o11 = __builtin_amdgcn_mfma_f32_32x32x16_bf16(pa1[c], vfr[c * 2 + 1], o11, 0, 0, 0);
        }
        __builtin_amdgcn_s_setprio(0);
    }

    // ---- split-KV combine: upper half dumps partials to LDS, lower half adds ----
    float l0 = (la0[0] + la0[1]) + (la0[2] + la0[3]);
    float l1 = (la1[0] + la1[1]) + (la1[2] + la1[3]);
    if (half == 1) {
#pragma unroll
        for (int g = 0; g < 4; g++) {
            *reinterpret_cast<f32x4*>(&Ol[wp][g][lane][0])      = f32x4{o00[4*g], o00[4*g+1], o00[4*g+2], o00[4*g+3]};
            *reinterpret_cast<f32x4*>(&Ol[wp][g + 4][lane][0])  = f32x4{o01[4*g], o01[4*g+1], o01[4*g+2], o01[4*g+3]};
            *reinterpret_cast<f32x4*>(&Ol[wp][g + 8][lane][0])  = f32x4{o10[4*g], o10[4*g+1], o10[4*g+2], o10[4*g+3]};
            *reinterpret_cast<f32x4*>(&Ol[wp][g + 12][lane][0]) = f32x4{o11[4*g], o11[4*g+1], o11[4*g+2], o11[4*g+3]};
        }
        Ll[wp][lane][0] = l0;
        Ll[wp][lane][1] = l1;
    }
    __syncthreads();
    if (half == 1) return;
    l0 += Ll[wp][lane][0];
    l1 += Ll[wp][lane][1];
#pragma unroll
    for (int g = 0; g < 4; g++) {
        f32x4 a0 = *reinterpret_cast<const f32x4*>(&Ol[wp][g][lane][0]);
        f32x4 a1 = *reinterpret_cast<const f32x4*>(&Ol[wp][g + 4][lane][0]);
        f32x4 a2 = *reinterpret_cast<const f32x4*>(&Ol[wp][g + 8][lane][0]);
        f32x4 a3 = *reinterpret_cast<const f32x4*>(&Ol[wp][g + 12][lane][0]);
#pragma unroll
        for (int j = 0; j < 4; j++) {
            o00[4*g + j] += a0[j];
            o01[4*g + j] += a1[j];
            o10[4*g + j] += a2[j];
            o11[4*g + j] += a3[j];
        }
    }

    // epilogue, tile 0 then tile 1
    {
        float l = l0;
        l += __shfl_xor(l, 32);
        float linv = 1.0f / l;
        int q0 = qt0 * 32;
#pragma unroll
        for (int reg = 0; reg < 16; reg++) {
            int qrow = (reg & 3) + 8 * (reg >> 2) + 4 * l5;
            float li = __shfl(linv, qrow);
            AO[(size_t)(b * TSEQ + q0 + qrow) * CDIM + h * 64 + l31]      = f2bf(o00[reg] * li);
            AO[(size_t)(b * TSEQ + q0 + qrow) * CDIM + h * 64 + 32 + l31] = f2bf(o01[reg] * li);
        }
    }
    {
        float l = l1;
        l += __shfl_xor(l, 32);
        float linv = 1.0f / l;
        int q0 = (qt0 + 1) * 32;
#pragma unroll
        for (int reg = 0; reg < 16; reg++) {
            int qrow = (reg & 3) + 8 * (reg >> 2) + 4 * l5;
            float li = __shfl(linv, qrow);
            AO[(size_t)(b * TSEQ + q0 + qrow) * CDIM + h * 64 + l31]      = f2bf(o10[reg] * li);
            AO[(size_t)(b * TSEQ + q0 + qrow) * CDIM + h * 64 + 32 + l31] = f2bf(o11[reg] * li);
        }
    }
}

extern "C" void kernel_launch(void* const* d_in, const int* in_sizes, int n_in,
                              void* d_out, int out_size, void* d_ws, size_t ws_size,
                              hipStream_t stream) {
    const float* x      = (const float*)d_in[0];
    const float* w_qkv  = (const float*)d_in[1];
    const float* b_qkv  = (const float*)d_in[2];
    const float* w_proj = (const float*)d_in[3];
    const float* b_proj = (const float*)d_in[4];
    float* out = (float*)d_out;

    u16* ws     = (u16*)d_ws;
    u16* Xb     = ws;                       // 4096x1024
    u16* Wqkvt  = Xb + 4194304;             // 3072x1024
    u16* Wprojt = Wqkvt + 3145728;          // 1024x1024
    u16* Qf     = Wprojt + 1048576;         // frag-ordered Q (c2-prescaled), 8 MB
    u16* Kf     = Qf + 4194304;             // frag-ordered K tiles, 8 MB
    u16* Vf     = Kf + 4194304;             // frag-ordered + PV-permuted V tiles, 8 MB
    u16* AO     = Vf + 4194304;             // 4096x1024
    // total ~50.3 MB

    prep_kernel<<<8192, 256, 0, stream>>>(x, w_qkv, w_proj, Xb, Wqkvt, Wprojt);
    gemm_qkv<<<dim3(32, 24), 256, 0, stream>>>(Xb, Wqkvt, b_qkv, Qf, Kf, Vf);
    attn_kernel<<<256, 512, 0, stream>>>(Qf, Kf, Vf, AO);
    gemm_proj<<<dim3(64, 8), 256, 0, stream>>>(AO, Wprojt, b_proj, out);
}

// Round 5
// 169.226 us; speedup vs baseline: 1.1084x; 1.1084x over previous
//
#include <hip/hip_runtime.h>

typedef unsigned short u16;
typedef unsigned int   u32;
typedef __bf16 bf16x8 __attribute__((ext_vector_type(8)));
typedef float  f32x4  __attribute__((ext_vector_type(4)));
typedef float  f32x16 __attribute__((ext_vector_type(16)));

#define TSEQ 2048
#define NHEAD 16
#define HDIM 64
#define CDIM 1024
#define N3   3072
#define MROWS 4096

__device__ __forceinline__ u16 f2bf(float f) {
    union { float f; u32 u; } v; v.f = f;
    u32 r = v.u + 0x7FFFu + ((v.u >> 16) & 1u);
    return (u16)(r >> 16);
}

// pack two fp32 -> packed bf16, 1-2 VALU ops.
__device__ __forceinline__ u32 pkbf(float a, float b) {
#if __has_builtin(__builtin_amdgcn_cvt_pk_bf16_f32)
    typedef __bf16 bf16x2 __attribute__((ext_vector_type(2)));
    bf16x2 t = __builtin_amdgcn_cvt_pk_bf16_f32(a, b);
    union { bf16x2 v; u32 u; } c; c.v = t; return c.u;
#else
    union { float f; u32 u; } ua, ub; ua.f = a; ub.f = b;
    u32 sel = 0x07060302, d;
    asm("v_perm_b32 %0, %1, %2, %3" : "=v"(d) : "v"(ub.u), "v"(ua.u), "v"(sel));
    return d;
#endif
}

// async global->LDS, 16B per lane (m97; GEMM staging only)
__device__ __forceinline__ void gld16(const u16* g, u16* l) {
    __builtin_amdgcn_global_load_lds(
        (const __attribute__((address_space(1))) u32*)g,
        (__attribute__((address_space(3))) u32*)l, 16, 0, 0);
}

// ---------------- merged prep: x->bf16 pack  +  both weight transposes ----------------
__global__ __launch_bounds__(256) void prep_kernel(const float* __restrict__ x,
                                                   const float* __restrict__ wqkv,
                                                   const float* __restrict__ wproj,
                                                   u16* __restrict__ Xb,
                                                   u16* __restrict__ oqkv, u16* __restrict__ oproj) {
    __shared__ float tile[32][33];
    const int bx = blockIdx.x;
    const int tid = threadIdx.x;
    if (bx < 4096) {  // pack region
        int i = bx * 256 + tid;
        float4 v = reinterpret_cast<const float4*>(x)[i];
        ushort4 o;
        o.x = f2bf(v.x); o.y = f2bf(v.y); o.z = f2bf(v.z); o.w = f2bf(v.w);
        reinterpret_cast<ushort4*>(Xb)[i] = o;
        return;
    }
    int idx = bx - 4096;
    int bnx = idx & 127;
    int k0  = (idx >> 7) * 32;
    const float* in; u16* out; int N, n0;
    if (bnx < 96) { in = wqkv;  out = oqkv;  N = 3072; n0 = bnx * 32; }
    else          { in = wproj; out = oproj; N = 1024; n0 = (bnx - 96) * 32; }
    int tx = tid & 31, ty = tid >> 5;  // (32, 8)
#pragma unroll
    for (int i = 0; i < 4; i++)
        tile[ty + i * 8][tx] = in[(size_t)(k0 + ty + i * 8) * N + n0 + tx];
    __syncthreads();
#pragma unroll
    for (int i = 0; i < 4; i++)
        out[(size_t)(n0 + ty + i * 8) * 1024 + k0 + tx] = f2bf(tile[tx][ty + i * 8]);
}

// ---------------- QKV GEMM: minimum 2-phase pipeline (T3) + aliased epilogue bounce ----------------
// Staging double-buffered (4x8KB); STAGE(t+1) issued BEFORE compute(t); ONE barrier per
// K-step (33 vs 64). Epilogue Im (32KB) aliases the staging region (dead after last barrier)
// -> LDS 32KB total, up to 5 blocks/CU.
// Qf chunk ((bh*64+qt)*4+kc): [lane=l5*32+q31][j] = Q[qt*32+q31][kc*16+l5*8+j]*c2
// Kf tile (bh*32+kb), chunk kc*2+nt: [lane][j] = K[nt*32+l31][kc*16+l5*8+j]
// Vf tile (bh*32+kb), chunk c*2+dt:  [lane][j] = V[c*16+(j>>2)*8+l5*4+(j&3)][dt*32+l31]
#define QKV_STAGE(K0, AOFF, BOFF)                                                            \
    _Pragma("unroll") for (int s = 0; s < 2; s++) {                                          \
        int i = tid + s * 256;                                                               \
        int r = sr + s * 64;                                                                 \
        gld16(&A[(size_t)(row0 + r) * CDIM + (K0) + sc_], &smem[(AOFF) + i * 8]);            \
        gld16(&Bt[(size_t)(col0 + r) * CDIM + (K0) + sc_], &smem[(BOFF) + i * 8]);           \
    }

#define QKV_COMPUTE(AOFF, BOFF)                                                              \
    {                                                                                        \
        bf16x8 af[4], bfr[4];                                                                \
        _Pragma("unroll") for (int t = 0; t < 4; t++) {                                      \
            af[t]  = *reinterpret_cast<const bf16x8*>(&smem[(AOFF) + (wm + t * 16 + lr) * 32 + lq * 8]); \
            bfr[t] = *reinterpret_cast<const bf16x8*>(&smem[(BOFF) + (wn + t * 16 + lr) * 32 + lq * 8]); \
        }                                                                                    \
        _Pragma("unroll") for (int mt = 0; mt < 4; mt++)                                     \
            _Pragma("unroll") for (int nt = 0; nt < 4; nt++)                                 \
                acc[mt][nt] = __builtin_amdgcn_mfma_f32_16x16x32_bf16(af[mt], bfr[nt], acc[mt][nt], 0, 0, 0); \
    }

__global__ __launch_bounds__(256) void gemm_qkv(const u16* __restrict__ A, const u16* __restrict__ Bt,
                                                const float* __restrict__ bias, u16* __restrict__ Qf,
                                                u16* __restrict__ Kf, u16* __restrict__ Vf) {
    __shared__ __align__(16) u16 smem[16384];  // 32 KB: staging dbuf {A0,B0,A1,B1}x8KB; aliased as Im
    u16* Im = smem;
    const int tid  = threadIdx.x;
    const int lane = tid & 63;
    const int wave = tid >> 6;
    const int wm = (wave >> 1) * 64;
    const int wn = (wave & 1) * 64;
    const int row0 = blockIdx.x * 128;
    const int col0 = blockIdx.y * 128;
    const int lr = lane & 15;
    const int lq = lane >> 4;
    const float c2 = 0.125f * 1.44269504088896f;

    f32x4 acc[4][4];
#pragma unroll
    for (int i = 0; i < 4; i++)
#pragma unroll
        for (int j = 0; j < 4; j++) acc[i][j] = f32x4{0.f, 0.f, 0.f, 0.f};

    const int sr = tid >> 2, sc_ = (tid & 3) * 8;

    // prologue: stage k-step 0 into buf0
    QKV_STAGE(0, 0, 4096);
    __syncthreads();
    // steady state: 2 K-steps per iteration, static buffer offsets
    for (int k0 = 0; k0 < CDIM - 64; k0 += 64) {
        QKV_STAGE(k0 + 32, 8192, 12288);   // -> buf1, overlaps compute(buf0)
        QKV_COMPUTE(0, 4096);
        __syncthreads();                    // drains vmcnt(0): buf1 ready; buf0 free
        QKV_STAGE(k0 + 64, 0, 4096);       // -> buf0, overlaps compute(buf1)
        QKV_COMPUTE(8192, 12288);
        __syncthreads();
    }
    // tail: step 960 is staged (buf0); stage 992, compute both
    QKV_STAGE(992, 8192, 12288);
    QKV_COMPUTE(0, 4096);
    __syncthreads();
    QKV_COMPUTE(8192, 12288);
    __syncthreads();   // staging dead from here; Im aliasing is safe

    const int region = col0 >> 10;
    const int h_base = (col0 & 1023) >> 6;
#pragma unroll
    for (int mt = 0; mt < 4; mt++) {
#pragma unroll
        for (int nt = 0; nt < 4; nt++) {
            int n_local = wn + nt * 16 + lr;
            float bv = bias[col0 + n_local];
            int h_local = n_local >> 6;
            int d = n_local & 63;
#pragma unroll
            for (int r = 0; r < 4; r++) {
                int m_local = wm + mt * 16 + lq * 4 + r;
                float v = acc[mt][nt][r] + bv;
                if (region == 0) {
                    int qt_local = m_local >> 5, q31 = m_local & 31;
                    int kc = d >> 4, l5b = (d >> 3) & 1, j = d & 7;
                    int lc = (h_local * 4 + qt_local) * 4 + kc;
                    Im[lc * 512 + (l5b * 32 + q31) * 8 + j] = f2bf(v * c2);
                } else if (region == 1) {
                    int kb_local = m_local >> 6, tr = m_local & 63;
                    int kc = d >> 4, l5b = (d >> 3) & 1, j = d & 7;
                    int nt2 = tr >> 5, p31 = tr & 31;
                    int lc = (h_local * 2 + kb_local) * 8 + kc * 2 + nt2;
                    Im[lc * 512 + (l5b * 32 + p31) * 8 + j] = f2bf(v);
                } else {
                    int kb_local = m_local >> 6, tr = m_local & 63;
                    int cV = tr >> 4, dt2 = d >> 5, p31 = d & 31;
                    int l5b = (tr >> 2) & 1;
                    int j = ((tr >> 3) & 1) * 4 + (tr & 3);
                    int lc = (h_local * 2 + kb_local) * 8 + cV * 2 + dt2;
                    Im[lc * 512 + (l5b * 32 + p31) * 8 + j] = f2bf(v);
                }
            }
        }
    }
    __syncthreads();
    const int bq = row0 >> 11;
    const int qrow0 = row0 & 2047;
#pragma unroll
    for (int s = 0; s < 8; s++) {
        int slot = s * 256 + tid;
        int lc = slot >> 6, li = slot & 63;
        uint4 data = *reinterpret_cast<const uint4*>(&Im[slot * 8]);
        if (region == 0) {
            int h_local = lc >> 4, qt_local = (lc >> 2) & 3, kc = lc & 3;
            size_t off = ((size_t)((bq * 16 + h_base + h_local) * 64 + (qrow0 >> 5) + qt_local) * 4 + kc) * 512
                       + li * 8;
            *reinterpret_cast<uint4*>(Qf + off) = data;
        } else {
            int h_local = lc >> 4, kb_local = (lc >> 3) & 1, cit = lc & 7;
            size_t off = (size_t)((bq * 16 + h_base + h_local) * 32 + (qrow0 >> 6) + kb_local) * 4096
                       + cit * 512 + li * 8;
            *reinterpret_cast<uint4*>((region == 1 ? Kf : Vf) + off) = data;
        }
    }
}

// ---------------- proj GEMM: 64x128 tile, BK=64, minimum 2-phase pipeline (T3) ----------------
#define PROJ_STAGE(K0, AOFF, BOFF)                                                           \
    _Pragma("unroll") for (int s = 0; s < 2; s++) {                                          \
        int i = tid + s * 256;                                                               \
        int kk = i >> 8, rr = (i >> 2) & 63, cc = i & 3;                                     \
        gld16(&A[(size_t)(row0 + rr) * CDIM + (K0) + kk * 32 + cc * 8], &smem[(AOFF) + i * 8]); \
    }                                                                                        \
    _Pragma("unroll") for (int s = 0; s < 4; s++) {                                          \
        int i = tid + s * 256;                                                               \
        int kk = i >> 9, rr = (i >> 2) & 127, cc = i & 3;                                    \
        gld16(&Bt[(size_t)(col0 + rr) * CDIM + (K0) + kk * 32 + cc * 8], &smem[(BOFF) + i * 8]); \
    }

#define PROJ_COMPUTE(AOFF, BOFF)                                                             \
    _Pragma("unroll") for (int kk = 0; kk < 2; kk++) {                                       \
        bf16x8 af[2], bfr[4];                                                                \
        _Pragma("unroll") for (int t = 0; t < 2; t++)                                        \
            af[t] = *reinterpret_cast<const bf16x8*>(&smem[(AOFF) + kk * 2048 + (wm + t * 16 + lr) * 32 + lq * 8]); \
        _Pragma("unroll") for (int t = 0; t < 4; t++)                                        \
            bfr[t] = *reinterpret_cast<const bf16x8*>(&smem[(BOFF) + kk * 4096 + (wn + t * 16 + lr) * 32 + lq * 8]); \
        _Pragma("unroll") for (int mt = 0; mt < 2; mt++)                                     \
            _Pragma("unroll") for (int nt = 0; nt < 4; nt++)                                 \
                acc[mt][nt] = __builtin_amdgcn_mfma_f32_16x16x32_bf16(af[mt], bfr[nt], acc[mt][nt], 0, 0, 0); \
    }

__global__ __launch_bounds__(256) void gemm_proj(const u16* __restrict__ A, const u16* __restrict__ Bt,
                                                 const float* __restrict__ bias, float* __restrict__ C) {
    __shared__ __align__(16) u16 smem[24576];  // 48 KB: {A0(8K),B0(16K),A1(8K),B1(16K)}
    const int tid  = threadIdx.x;
    const int lane = tid & 63;
    const int wave = tid >> 6;
    const int wm = (wave >> 1) * 32;
    const int wn = (wave & 1) * 64;
    const int row0 = blockIdx.x * 64;
    const int col0 = blockIdx.y * 128;
    const int lr = lane & 15;
    const int lq = lane >> 4;

    f32x4 acc[2][4];
#pragma unroll
    for (int i = 0; i < 2; i++)
#pragma unroll
        for (int j = 0; j < 4; j++) acc[i][j] = f32x4{0.f, 0.f, 0.f, 0.f};

    // buf0: A@0, B@4096; buf1: A@12288, B@16384 (u16 offsets)
    PROJ_STAGE(0, 0, 4096);
    __syncthreads();
    for (int k0 = 0; k0 < CDIM - 128; k0 += 128) {
        PROJ_STAGE(k0 + 64, 12288, 16384);
        PROJ_COMPUTE(0, 4096);
        __syncthreads();
        PROJ_STAGE(k0 + 128, 0, 4096);
        PROJ_COMPUTE(12288, 16384);
        __syncthreads();
    }
    PROJ_STAGE(960, 12288, 16384);
    PROJ_COMPUTE(0, 4096);
    __syncthreads();
    PROJ_COMPUTE(12288, 16384);

#pragma unroll
    for (int mt = 0; mt < 2; mt++) {
#pragma unroll
        for (int nt = 0; nt < 4; nt++) {
            int col = col0 + wn + nt * 16 + lr;
            float bv = bias[col];
#pragma unroll
            for (int r = 0; r < 4; r++) {
                int row = row0 + wm + mt * 16 + lq * 4 + r;
                C[(size_t)row * CDIM + col] = acc[mt][nt][r] + bv;
            }
        }
    }
}

// ---------------- flash attention: EXACT round-0 version (verified 45.2 us) ----------------
__global__ __launch_bounds__(256, 1) void attn_kernel(const u16* __restrict__ Qf,
                                                      const u16* __restrict__ Kf,
                                                      const u16* __restrict__ Vf,
                                                      u16* __restrict__ AO) {
    const int id = blockIdx.x;            // 256 blocks; blocks of one (b,h) share id%8 -> same XCD
    const int bh = id & 31;
    const int qb = id >> 5;               // [0,8)
    const int b = bh >> 4, h = bh & 15;
    const int tid = threadIdx.x, lane = tid & 63, wave = tid >> 6;
    const int l31 = lane & 31, l5 = lane >> 5;
    const int qt0 = qb * 8 + wave * 2;    // this wave's two 32-q tiles

    // Q B-frags (c2-prescaled), frag-ordered, coalesced
    bf16x8 qa0[4], qa1[4];
    {
        const u16* qp = Qf + ((size_t)(bh * 64 + qt0) * 4) * 512 + lane * 8;
#pragma unroll
        for (int kc = 0; kc < 4; kc++) {
            qa0[kc] = *reinterpret_cast<const bf16x8*>(qp + kc * 512);
            qa1[kc] = *reinterpret_cast<const bf16x8*>(qp + 2048 + kc * 512);
        }
    }
    f32x16 o00, o01, o10, o11, zc;
#pragma unroll
    for (int i = 0; i < 16; i++) { o00[i] = 0.f; o01[i] = 0.f; o10[i] = 0.f; o11[i] = 0.f; zc[i] = 0.f; }
    float l0 = 0.f, l1 = 0.f;

    const u16* kcur = Kf + (size_t)bh * 32 * 4096 + lane * 8;
    const u16* vcur = Vf + (size_t)bh * 32 * 4096 + lane * 8;

    bf16x8 ka[8];
#pragma unroll
    for (int i = 0; i < 8; i++) ka[i] = *reinterpret_cast<const bf16x8*>(kcur + i * 512);

    for (int kb = 0; kb < 32; kb++) {
        // S^T = K * Q^T for both q-tiles (shared ka)
        f32x16 st00, st01, st10, st11;
        st00 = __builtin_amdgcn_mfma_f32_32x32x16_bf16(ka[0], qa0[0], zc, 0, 0, 0);
        st01 = __builtin_amdgcn_mfma_f32_32x32x16_bf16(ka[1], qa0[0], zc, 0, 0, 0);
        st10 = __builtin_amdgcn_mfma_f32_32x32x16_bf16(ka[0], qa1[0], zc, 0, 0, 0);
        st11 = __builtin_amdgcn_mfma_f32_32x32x16_bf16(ka[1], qa1[0], zc, 0, 0, 0);
#pragma unroll
        for (int kc = 1; kc < 4; kc++) {
            st00 = __builtin_amdgcn_mfma_f32_32x32x16_bf16(ka[kc * 2],     qa0[kc], st00, 0, 0, 0);
            st01 = __builtin_amdgcn_mfma_f32_32x32x16_bf16(ka[kc * 2 + 1], qa0[kc], st01, 0, 0, 0);
            st10 = __builtin_amdgcn_mfma_f32_32x32x16_bf16(ka[kc * 2],     qa1[kc], st10, 0, 0, 0);
            st11 = __builtin_amdgcn_mfma_f32_32x32x16_bf16(ka[kc * 2 + 1], qa1[kc], st11, 0, 0, 0);
        }
        // V-frags for this tile + prefetch next tile's K in place (round-7 pattern)
        bf16x8 vfr[8];
#pragma unroll
        for (int i = 0; i < 8; i++) vfr[i] = *reinterpret_cast<const bf16x8*>(vcur + i * 512);
        const u16* knext = kcur + (kb < 31 ? 4096 : 0);
#pragma unroll
        for (int i = 0; i < 8; i++) ka[i] = *reinterpret_cast<const bf16x8*>(knext + i * 512);
        kcur = knext;
        vcur += 4096;
        // softmax: P = exp2(st) (prescaled; |st| < ~9, in range)
        bf16x8 pa0[4], pa1[4];
        {
            float pe[16];
#pragma unroll
            for (int r = 0; r < 16; r++) { pe[r] = __builtin_amdgcn_exp2f(st00[r]); l0 += pe[r]; }
            union { bf16x8 v; u32 w[4]; } ua, ub;
#pragma unroll
            for (int j = 0; j < 4; j++) { ua.w[j] = pkbf(pe[2 * j], pe[2 * j + 1]); ub.w[j] = pkbf(pe[8 + 2 * j], pe[8 + 2 * j + 1]); }
            pa0[0] = ua.v; pa0[1] = ub.v;
#pragma unroll
            for (int r = 0; r < 16; r++) { pe[r] = __builtin_amdgcn_exp2f(st01[r]); l0 += pe[r]; }
#pragma unroll
            for (int j = 0; j < 4; j++) { ua.w[j] = pkbf(pe[2 * j], pe[2 * j + 1]); ub.w[j] = pkbf(pe[8 + 2 * j], pe[8 + 2 * j + 1]); }
            pa0[2] = ua.v; pa0[3] = ub.v;
#pragma unroll
            for (int r = 0; r < 16; r++) { pe[r] = __builtin_amdgcn_exp2f(st10[r]); l1 += pe[r]; }
#pragma unroll
            for (int j = 0; j < 4; j++) { ua.w[j] = pkbf(pe[2 * j], pe[2 * j + 1]); ub.w[j] = pkbf(pe[8 + 2 * j], pe[8 + 2 * j + 1]); }
            pa1[0] = ua.v; pa1[1] = ub.v;
#pragma unroll
            for (int r = 0; r < 16; r++) { pe[r] = __builtin_amdgcn_exp2f(st11[r]); l1 += pe[r]; }
#pragma unroll
            for (int j = 0; j < 4; j++) { ua.w[j] = pkbf(pe[2 * j], pe[2 * j + 1]); ub.w[j] = pkbf(pe[8 + 2 * j], pe[8 + 2 * j + 1]); }
            pa1[2] = ua.v; pa1[3] = ub.v;
        }
        // O += P V (V rows pre-permuted to match P's register key order)
#pragma unroll
        for (int c = 0; c < 4; c++) {
            o00 = __builtin_amdgcn_mfma_f32_32x32x16_bf16(pa0[c], vfr[c * 2],     o00, 0, 0, 0);
            o01 = __builtin_amdgcn_mfma_f32_32x32x16_bf16(pa0[c], vfr[c * 2 + 1], o01, 0, 0, 0);
            o10 = __builtin_amdgcn_mfma_f32_32x32x16_bf16(pa1[c], vfr[c * 2],     o10, 0, 0, 0);
            o11 = __builtin_amdgcn_mfma_f32_32x32x16_bf16(pa1[c], vfr[c * 2 + 1], o11, 0, 0, 0);
        }
    }
    // epilogue, tile 0 then tile 1
    {
        float l = l0;
        l += __shfl_xor(l, 32);
        float linv = 1.0f / l;
        int q0 = qt0 * 32;
#pragma unroll
        for (int reg = 0; reg < 16; reg++) {
            int qrow = (reg & 3) + 8 * (reg >> 2) + 4 * l5;
            float li = __shfl(linv, qrow);
            AO[(size_t)(b * TSEQ + q0 + qrow) * CDIM + h * 64 + l31]      = f2bf(o00[reg] * li);
            AO[(size_t)(b * TSEQ + q0 + qrow) * CDIM + h * 64 + 32 + l31] = f2bf(o01[reg] * li);
        }
    }
    {
        float l = l1;
        l += __shfl_xor(l, 32);
        float linv = 1.0f / l;
        int q0 = (qt0 + 1) * 32;
#pragma unroll
        for (int reg = 0; reg < 16; reg++) {
            int qrow = (reg & 3) + 8 * (reg >> 2) + 4 * l5;
            float li = __shfl(linv, qrow);
            AO[(size_t)(b * TSEQ + q0 + qrow) * CDIM + h * 64 + l31]      = f2bf(o10[reg] * li);
            AO[(size_t)(b * TSEQ + q0 + qrow) * CDIM + h * 64 + 32 + l31] = f2bf(o11[reg] * li);
        }
    }
}

extern "C" void kernel_launch(void* const* d_in, const int* in_sizes, int n_in,
                              void* d_out, int out_size, void* d_ws, size_t ws_size,
                              hipStream_t stream) {
    const float* x      = (const float*)d_in[0];
    const float* w_qkv  = (const float*)d_in[1];
    const float* b_qkv  = (const float*)d_in[2];
    const float* w_proj = (const float*)d_in[3];
    const float* b_proj = (const float*)d_in[4];
    float* out = (float*)d_out;

    u16* ws     = (u16*)d_ws;
    u16* Xb     = ws;                       // 4096x1024
    u16* Wqkvt  = Xb + 4194304;             // 3072x1024
    u16* Wprojt = Wqkvt + 3145728;          // 1024x1024
    u16* Qf     = Wprojt + 1048576;         // frag-ordered Q (c2-prescaled), 8 MB
    u16* Kf     = Qf + 4194304;             // frag-ordered K tiles, 8 MB
    u16* Vf     = Kf + 4194304;             // frag-ordered + PV-permuted V tiles, 8 MB
    u16* AO     = Vf + 4194304;             // 4096x1024
    // total ~50.3 MB

    prep_kernel<<<8192, 256, 0, stream>>>(x, w_qkv, w_proj, Xb, Wqkvt, Wprojt);
    gemm_qkv<<<dim3(32, 24), 256, 0, stream>>>(Xb, Wqkvt, b_qkv, Qf, Kf, Vf);
    attn_kernel<<<256, 256, 0, stream>>>(Qf, Kf, Vf, AO);
    gemm_proj<<<dim3(64, 8), 256, 0, stream>>>(AO, Wprojt, b_proj, out);
}